// Round 6
// baseline (184.040 us; speedup 1.0000x reference)
//
#include <hip/hip_runtime.h>

// B=4, C=12, D=32, H=128, W=128. S = D*H*W = 524288 voxels per b.
// One pass: softmax over C, accumulate 32 scalars per b, finalize 4 losses.
// R2: 2->4 blocks/CU: 59->48us. R4: float2+TRANS cuts: neutral. R5: ping-pong
//   + non-atomic partials: +8us (finalize regression; reverted).
// R6 DIAGNOSTIC (REP=2): marg_main VGPR=40, Occ=38%, VALUBusy=33%, FETCH=106MB
//   (no over-fetch, no spills); pass2 (L3) ~13us vs pass1 (HBM) ~47us.
//   => memory-LATENCY/concurrency bound: per-CU outstanding ~3.3KB only;
//   launch_bounds(256,4) caps 16 waves/CU. VGPR=40 allows 8 waves/SIMD.
// R7: grid 2048 blocks (8 blocks/CU = 32 waves/CU = 100% occ), ITERS 4->2,
//   launch_bounds(256,8). Single variable: wave concurrency.

#define S2 262144           // S/2 float2 groups per (b,c) plane
#define BLOCKS_PER_B 512
#define THREADS 256
#define ITERS 2             // 2 float2 groups (4 voxels) per thread
#define NVOX 524288.0f
#define SMOOTH 1e-5f

#define WRED(v) { v += __shfl_down(v,32); v += __shfl_down(v,16); \
                  v += __shfl_down(v,8);  v += __shfl_down(v,4);  \
                  v += __shfl_down(v,2);  v += __shfl_down(v,1); }

// Per-voxel processing; COMP in {x,y}. Numerics identical to R4.
// id1 = t<=4 ? 2t+1 : t+5 ; id2 = t<=3 ? 2t+2 : -1
#define PROC2(X, TG, COMP) do {                                                \
  float xv[12];                                                                \
  _Pragma("unroll")                                                            \
  for (int c = 0; c < 12; ++c) xv[c] = X[c].COMP;                              \
  const int tgt = TG.COMP;                                                     \
  float m = xv[0];                                                             \
  _Pragma("unroll")                                                            \
  for (int c = 1; c < 12; ++c) m = fmaxf(m, xv[c]);                            \
  float e[12]; float es = 0.f;                                                 \
  _Pragma("unroll")                                                            \
  for (int c = 0; c < 12; ++c) { e[c] = __expf(xv[c] - m); es += e[c]; }       \
  const float r = __builtin_amdgcn_rcpf(es);                                   \
  float p[12];                                                                 \
  _Pragma("unroll")                                                            \
  for (int c = 0; c < 12; ++c) {                                               \
    p[c] = e[c] * r;                                                           \
    aZ[c] += p[c] * p[c];                                                      \
    aP[c] += p[c];                                                             \
  }                                                                            \
  float q = 1.f;                                                               \
  _Pragma("unroll")                                                            \
  for (int c = 1; c < 12; ++c) q = __builtin_fmaf(p[c], q, q);                 \
  const float g0 = p[0];                                                       \
  float g1 = 0.f, g2 = 0.f;                                                    \
  _Pragma("unroll")                                                            \
  for (int c = 1; c < 12; ++c) {                                               \
    if (c==1||c==3||c==5||c==7||c==9||c==10||c==11) g1 = (id1==c) ? p[c] : g1; \
    else                                            g2 = (id2==c) ? p[c] : g2; \
  }                                                                            \
  const bool t0 = (tgt == 0);                                                  \
  const bool t1 = (tgt == id1);                                                \
  const bool t2 = (tgt == id2);                                                \
  c0 += t0 ? 1.f : 0.f;  c1 += t1 ? 1.f : 0.f;  c2 += t2 ? 1.f : 0.f;          \
  p0S += t0 ? g0 : 0.f;  p1S += t1 ? g1 : 0.f;  p2S += t2 ? g2 : 0.f;          \
  const float pt = t1 ? g1 : (t2 ? g2 : 0.f);                                  \
  cesE += __logf(q * __builtin_amdgcn_rcpf(1.f + pt));                         \
  float s3 = __expf(g0) + __expf(g1);                                          \
  if (v2) s3 += __expf(g2);                                                    \
  const float gt = t0 ? g0 : (t1 ? g1 : g2);                                   \
  ces += __logf(s3) - gt;                                                      \
} while (0)

__global__ void zero_acc(float* __restrict__ acc) {
  acc[threadIdx.x] = 0.f;   // 4 b * 64 slots
}

// Slot layout per b (stride 64):
//  0: ces   1: cesE   2,3,4: cnt0,cnt1,cnt2   5,6,7: pTgt0,pTgt1,pTgt2
//  8..19: z[c] = sum p_c^2    20..31: pSum[c] = sum p_c
__global__ __launch_bounds__(THREADS, 8)
void marg_main(const float2* __restrict__ inp, const int2* __restrict__ tgtp,
               const int* __restrict__ task_id, float* __restrict__ acc) {
  const int b   = blockIdx.x / BLOCKS_PER_B;
  const int blk = blockIdx.x % BLOCKS_PER_B;
  const int t   = task_id[b];
  const int id1 = (t <= 4) ? 2*t + 1 : t + 5;
  const int id2 = (t <= 3) ? 2*t + 2 : -1;
  const bool v2 = (id2 >= 0);

  const float2* inB = inp  + (size_t)b * 12 * S2;
  const int2*   tgB = tgtp + (size_t)b * S2;

  float aZ[12], aP[12];
  #pragma unroll
  for (int c = 0; c < 12; ++c) { aZ[c]=0.f; aP[c]=0.f; }
  float ces=0.f, cesE=0.f, c0=0.f, c1=0.f, c2=0.f, p0S=0.f, p1S=0.f, p2S=0.f;

  #pragma unroll 1
  for (int it = 0; it < ITERS; ++it) {
    const int s = blk * (ITERS * THREADS) + it * THREADS + (int)threadIdx.x;
    float2 x[12];
    #pragma unroll
    for (int c = 0; c < 12; ++c) x[c] = inB[c * S2 + s];
    const int2 tg = tgB[s];
    PROC2(x, tg, x); PROC2(x, tg, y);
  }

  WRED(ces); WRED(cesE); WRED(c0); WRED(c1); WRED(c2);
  WRED(p0S); WRED(p1S); WRED(p2S);
  #pragma unroll
  for (int c = 0; c < 12; ++c) { WRED(aZ[c]); WRED(aP[c]); }

  __shared__ float red[4][32];
  const int lane = threadIdx.x & 63;
  const int wv   = threadIdx.x >> 6;
  if (lane == 0) {
    float* rw = red[wv];
    rw[0]=ces; rw[1]=cesE; rw[2]=c0; rw[3]=c1; rw[4]=c2;
    rw[5]=p0S; rw[6]=p1S; rw[7]=p2S;
    #pragma unroll
    for (int c = 0; c < 12; ++c) { rw[8+c]=aZ[c]; rw[20+c]=aP[c]; }
  }
  __syncthreads();
  if (threadIdx.x < 32) {
    const float sv = red[0][threadIdx.x] + red[1][threadIdx.x]
                   + red[2][threadIdx.x] + red[3][threadIdx.x];
    atomicAdd(acc + b * 64 + threadIdx.x, sv);
  }
}

__global__ void finalize(const float* __restrict__ acc,
                         const int* __restrict__ task_id,
                         float* __restrict__ out) {
  if (threadIdx.x != 0) return;
  float lmd = 0.f, lmce = 0.f, led = 0.f, lece = 0.f;
  for (int b = 0; b < 4; ++b) {
    const float* a = acc + b * 64;
    const int t   = task_id[b];
    const int id1 = (t <= 4) ? 2*t + 1 : t + 5;
    const int id2 = (t <= 3) ? 2*t + 2 : -1;

    lmce += a[0] / NVOX;
    lece += a[1] / NVOX;

    const float d0 = (2.f*a[5] + SMOOTH) / (a[8 + 0]   + a[2] + SMOOTH);
    const float d1 = (2.f*a[6] + SMOOTH) / (a[8 + id1] + a[3] + SMOOTH);
    float d2 = 1.f;
    if (id2 >= 0)
      d2 = (2.f*a[7] + SMOOTH) / (a[8 + id2] + a[4] + SMOOTH);
    lmd += (1.f - d0) + (1.f - d1) + (1.f - d2);

    led += SMOOTH / (a[8] + SMOOTH);
    for (int c = 1; c < 12; ++c) {
      const float ptc  = (c == id1) ? a[6] : ((c == id2) ? a[7] : 0.f);
      const float cntc = (c == id1) ? a[3] : ((c == id2) ? a[4] : 0.f);
      const float inter = a[20 + c] - ptc;
      const float ye    = NVOX - cntc;
      led += (2.f*inter + SMOOTH) / (a[8 + c] + ye + SMOOTH);
    }
  }
  out[0] = lmd  * 0.25f;
  out[1] = lmce * 0.25f;
  out[2] = led  * 0.25f;
  out[3] = lece * 0.25f;
}

extern "C" void kernel_launch(void* const* d_in, const int* in_sizes, int n_in,
                              void* d_out, int out_size, void* d_ws, size_t ws_size,
                              hipStream_t stream) {
  const float* inputs  = (const float*)d_in[0];
  const int*   targets = (const int*)d_in[1];
  const int*   task_id = (const int*)d_in[2];
  float* out = (float*)d_out;
  float* acc = (float*)d_ws;

  zero_acc<<<1, 256, 0, stream>>>(acc);
  marg_main<<<dim3(4 * BLOCKS_PER_B), THREADS, 0, stream>>>(
      (const float2*)inputs, (const int2*)targets, task_id, acc);
  finalize<<<1, 64, 0, stream>>>(acc, task_id, out);
}

// Round 7
// 167.327 us; speedup vs baseline: 1.0999x; 1.0999x over previous
//
#include <hip/hip_runtime.h>

// B=4, C=12, D=32, H=128, W=128. S = D*H*W = 524288 voxels per b.
// One pass: softmax over C, accumulate 32 scalars per b, finalize 4 losses.
// R2: 2->4 blocks/CU: 59->48us. R4: float2+TRANS cuts: neutral.
// R6 DIAGNOSTIC (REP=2): VGPR=40, Occ=38% (GRID-limited: 1024 blk = 4/CU),
//   VALUBusy=33%, pass2(L3)~13us vs pass1(HBM)~47us => latency/concurrency
//   bound, need more waves in flight.
// R7: grid 2048 + launch_bounds(256,8) -> REGRESSION 65us: bounds=8 capped
//   allocator at 64 VGPR -> spills (WRITE_SIZE=62MB scratch!, VALUBusy 17%).
//   Lesson: 2nd arg was never needed -- at VGPR=40, 8 blocks/CU already fit.
// R8: single variable: keep grid 2048 (ITERS=2), REVERT bounds to (256,4).
//   Allocator free (cap 128) -> natural ~40 VGPR, no spills; HW schedules
//   8 blocks/CU. Predict: WRITE->~0, Occ 80-95%, dur ~30us.

#define S2 262144           // S/2 float2 groups per (b,c) plane
#define BLOCKS_PER_B 512
#define THREADS 256
#define ITERS 2             // 2 float2 groups (4 voxels) per thread
#define NVOX 524288.0f
#define SMOOTH 1e-5f

#define WRED(v) { v += __shfl_down(v,32); v += __shfl_down(v,16); \
                  v += __shfl_down(v,8);  v += __shfl_down(v,4);  \
                  v += __shfl_down(v,2);  v += __shfl_down(v,1); }

// Per-voxel processing; COMP in {x,y}. Numerics identical to R4.
// id1 = t<=4 ? 2t+1 : t+5 ; id2 = t<=3 ? 2t+2 : -1
#define PROC2(X, TG, COMP) do {                                                \
  float xv[12];                                                                \
  _Pragma("unroll")                                                            \
  for (int c = 0; c < 12; ++c) xv[c] = X[c].COMP;                              \
  const int tgt = TG.COMP;                                                     \
  float m = xv[0];                                                             \
  _Pragma("unroll")                                                            \
  for (int c = 1; c < 12; ++c) m = fmaxf(m, xv[c]);                            \
  float e[12]; float es = 0.f;                                                 \
  _Pragma("unroll")                                                            \
  for (int c = 0; c < 12; ++c) { e[c] = __expf(xv[c] - m); es += e[c]; }       \
  const float r = __builtin_amdgcn_rcpf(es);                                   \
  float p[12];                                                                 \
  _Pragma("unroll")                                                            \
  for (int c = 0; c < 12; ++c) {                                               \
    p[c] = e[c] * r;                                                           \
    aZ[c] += p[c] * p[c];                                                      \
    aP[c] += p[c];                                                             \
  }                                                                            \
  float q = 1.f;                                                               \
  _Pragma("unroll")                                                            \
  for (int c = 1; c < 12; ++c) q = __builtin_fmaf(p[c], q, q);                 \
  const float g0 = p[0];                                                       \
  float g1 = 0.f, g2 = 0.f;                                                    \
  _Pragma("unroll")                                                            \
  for (int c = 1; c < 12; ++c) {                                               \
    if (c==1||c==3||c==5||c==7||c==9||c==10||c==11) g1 = (id1==c) ? p[c] : g1; \
    else                                            g2 = (id2==c) ? p[c] : g2; \
  }                                                                            \
  const bool t0 = (tgt == 0);                                                  \
  const bool t1 = (tgt == id1);                                                \
  const bool t2 = (tgt == id2);                                                \
  c0 += t0 ? 1.f : 0.f;  c1 += t1 ? 1.f : 0.f;  c2 += t2 ? 1.f : 0.f;          \
  p0S += t0 ? g0 : 0.f;  p1S += t1 ? g1 : 0.f;  p2S += t2 ? g2 : 0.f;          \
  const float pt = t1 ? g1 : (t2 ? g2 : 0.f);                                  \
  cesE += __logf(q * __builtin_amdgcn_rcpf(1.f + pt));                         \
  float s3 = __expf(g0) + __expf(g1);                                          \
  if (v2) s3 += __expf(g2);                                                    \
  const float gt = t0 ? g0 : (t1 ? g1 : g2);                                   \
  ces += __logf(s3) - gt;                                                      \
} while (0)

__global__ void zero_acc(float* __restrict__ acc) {
  acc[threadIdx.x] = 0.f;   // 4 b * 64 slots
}

// Slot layout per b (stride 64):
//  0: ces   1: cesE   2,3,4: cnt0,cnt1,cnt2   5,6,7: pTgt0,pTgt1,pTgt2
//  8..19: z[c] = sum p_c^2    20..31: pSum[c] = sum p_c
__global__ __launch_bounds__(THREADS, 4)
void marg_main(const float2* __restrict__ inp, const int2* __restrict__ tgtp,
               const int* __restrict__ task_id, float* __restrict__ acc) {
  const int b   = blockIdx.x / BLOCKS_PER_B;
  const int blk = blockIdx.x % BLOCKS_PER_B;
  const int t   = task_id[b];
  const int id1 = (t <= 4) ? 2*t + 1 : t + 5;
  const int id2 = (t <= 3) ? 2*t + 2 : -1;
  const bool v2 = (id2 >= 0);

  const float2* inB = inp  + (size_t)b * 12 * S2;
  const int2*   tgB = tgtp + (size_t)b * S2;

  float aZ[12], aP[12];
  #pragma unroll
  for (int c = 0; c < 12; ++c) { aZ[c]=0.f; aP[c]=0.f; }
  float ces=0.f, cesE=0.f, c0=0.f, c1=0.f, c2=0.f, p0S=0.f, p1S=0.f, p2S=0.f;

  #pragma unroll 1
  for (int it = 0; it < ITERS; ++it) {
    const int s = blk * (ITERS * THREADS) + it * THREADS + (int)threadIdx.x;
    float2 x[12];
    #pragma unroll
    for (int c = 0; c < 12; ++c) x[c] = inB[c * S2 + s];
    const int2 tg = tgB[s];
    PROC2(x, tg, x); PROC2(x, tg, y);
  }

  WRED(ces); WRED(cesE); WRED(c0); WRED(c1); WRED(c2);
  WRED(p0S); WRED(p1S); WRED(p2S);
  #pragma unroll
  for (int c = 0; c < 12; ++c) { WRED(aZ[c]); WRED(aP[c]); }

  __shared__ float red[4][32];
  const int lane = threadIdx.x & 63;
  const int wv   = threadIdx.x >> 6;
  if (lane == 0) {
    float* rw = red[wv];
    rw[0]=ces; rw[1]=cesE; rw[2]=c0; rw[3]=c1; rw[4]=c2;
    rw[5]=p0S; rw[6]=p1S; rw[7]=p2S;
    #pragma unroll
    for (int c = 0; c < 12; ++c) { rw[8+c]=aZ[c]; rw[20+c]=aP[c]; }
  }
  __syncthreads();
  if (threadIdx.x < 32) {
    const float sv = red[0][threadIdx.x] + red[1][threadIdx.x]
                   + red[2][threadIdx.x] + red[3][threadIdx.x];
    atomicAdd(acc + b * 64 + threadIdx.x, sv);
  }
}

__global__ void finalize(const float* __restrict__ acc,
                         const int* __restrict__ task_id,
                         float* __restrict__ out) {
  if (threadIdx.x != 0) return;
  float lmd = 0.f, lmce = 0.f, led = 0.f, lece = 0.f;
  for (int b = 0; b < 4; ++b) {
    const float* a = acc + b * 64;
    const int t   = task_id[b];
    const int id1 = (t <= 4) ? 2*t + 1 : t + 5;
    const int id2 = (t <= 3) ? 2*t + 2 : -1;

    lmce += a[0] / NVOX;
    lece += a[1] / NVOX;

    const float d0 = (2.f*a[5] + SMOOTH) / (a[8 + 0]   + a[2] + SMOOTH);
    const float d1 = (2.f*a[6] + SMOOTH) / (a[8 + id1] + a[3] + SMOOTH);
    float d2 = 1.f;
    if (id2 >= 0)
      d2 = (2.f*a[7] + SMOOTH) / (a[8 + id2] + a[4] + SMOOTH);
    lmd += (1.f - d0) + (1.f - d1) + (1.f - d2);

    led += SMOOTH / (a[8] + SMOOTH);
    for (int c = 1; c < 12; ++c) {
      const float ptc  = (c == id1) ? a[6] : ((c == id2) ? a[7] : 0.f);
      const float cntc = (c == id1) ? a[3] : ((c == id2) ? a[4] : 0.f);
      const float inter = a[20 + c] - ptc;
      const float ye    = NVOX - cntc;
      led += (2.f*inter + SMOOTH) / (a[8 + c] + ye + SMOOTH);
    }
  }
  out[0] = lmd  * 0.25f;
  out[1] = lmce * 0.25f;
  out[2] = led  * 0.25f;
  out[3] = lece * 0.25f;
}

extern "C" void kernel_launch(void* const* d_in, const int* in_sizes, int n_in,
                              void* d_out, int out_size, void* d_ws, size_t ws_size,
                              hipStream_t stream) {
  const float* inputs  = (const float*)d_in[0];
  const int*   targets = (const int*)d_in[1];
  const int*   task_id = (const int*)d_in[2];
  float* out = (float*)d_out;
  float* acc = (float*)d_ws;

  zero_acc<<<1, 256, 0, stream>>>(acc);
  marg_main<<<dim3(4 * BLOCKS_PER_B), THREADS, 0, stream>>>(
      (const float2*)inputs, (const int2*)targets, task_id, acc);
  finalize<<<1, 64, 0, stream>>>(acc, task_id, out);
}